// Round 1
// baseline (5166.113 us; speedup 1.0000x reference)
//
#include <hip/hip_runtime.h>

// ---------------------------------------------------------------------------
// 2-layer tanh RNN, B=64, T=512, I=256, H=512.
// Strategy (round 1 baseline):
//   - convert x, weights, h_0 to fp16 in ws (fp32 accumulate in MFMA)
//   - 513 pipelined step kernels: step s runs layer0@t=s (blocks 0..31) and
//     layer1@t=s-1 (blocks 32..63). Kernel boundary = global sync.
//   - per block: 64 batches x 16 cols, one 16x16x32_f16 MFMA tile per wave,
//     fragments loaded directly from global fp16 (L1/L2 hot, no LDS).
// ---------------------------------------------------------------------------

#define kB 64
#define kT 512
#define kI 256
#define kH 512

typedef _Float16 half8 __attribute__((ext_vector_type(8)));
typedef float floatx4 __attribute__((ext_vector_type(4)));

// ws layout in fp16 elements
constexpr size_t X16_OFF   = 0;                                  // [B][T][I]
constexpr size_t X16_N     = (size_t)kB * kT * kI;               // 8,388,608
constexpr size_t OUT0_OFF  = X16_OFF + X16_N;                    // [T][B][H]
constexpr size_t OUT0_N    = (size_t)kT * kB * kH;               // 16,777,216
constexpr size_t WIH0_OFF  = OUT0_OFF + OUT0_N;                  // [H][I]
constexpr size_t WIH0_N    = (size_t)kH * kI;
constexpr size_t WHH0_OFF  = WIH0_OFF + WIH0_N;                  // [H][H]
constexpr size_t WHH0_N    = (size_t)kH * kH;
constexpr size_t WIH1_OFF  = WHH0_OFF + WHH0_N;                  // [H][H]
constexpr size_t WIH1_N    = (size_t)kH * kH;
constexpr size_t WHH1_OFF  = WIH1_OFF + WIH1_N;                  // [H][H]
constexpr size_t WHH1_N    = (size_t)kH * kH;
constexpr size_t HINIT0_OFF = WHH1_OFF + WHH1_N;                 // [B][H]
constexpr size_t HINIT1_OFF = HINIT0_OFF + (size_t)kB * kH;      // [B][H]
constexpr size_t H1BUF_OFF  = HINIT1_OFF + (size_t)kB * kH;      // [2][B][H]

__global__ void f32_to_f16_kernel(const float* __restrict__ src,
                                  _Float16* __restrict__ dst, size_t n) {
    size_t i = (size_t)blockIdx.x * blockDim.x + threadIdx.x;
    size_t stride = (size_t)gridDim.x * blockDim.x;
    for (; i < n; i += stride) dst[i] = (_Float16)src[i];
}

template <int K>
__device__ inline floatx4 mfma_rows(const _Float16* __restrict__ arow,
                                    const _Float16* __restrict__ brow,
                                    floatx4 acc, int q) {
#pragma unroll
    for (int k0 = 0; k0 < K; k0 += 32) {
        half8 a = *(const half8*)(arow + k0 + q * 8);
        half8 b = *(const half8*)(brow + k0 + q * 8);
        acc = __builtin_amdgcn_mfma_f32_16x16x32_f16(a, b, acc, 0, 0, 0);
    }
    return acc;
}

// grid: 64 blocks x 256 threads. blocks 0..31: layer0 (t=s); 32..63: layer1 (t=s-1)
__global__ __launch_bounds__(256) void step_kernel(
    _Float16* __restrict__ ws16, float* __restrict__ out1,
    const float* __restrict__ bih0, const float* __restrict__ bhh0,
    const float* __restrict__ bih1, const float* __restrict__ bhh1, int s) {
    const int blk = blockIdx.x;
    const int tid = threadIdx.x;
    const int wave = tid >> 6;
    const int lane = tid & 63;
    const int r = lane & 15;    // A: m-row / B: n-row selector
    const int q = lane >> 4;    // k-subchunk selector
    const int m0 = wave * 16;   // batch tile base

    floatx4 acc = {0.f, 0.f, 0.f, 0.f};

    if (blk < 32) {
        // ---- layer 0, t = s ----
        if (s >= kT) return;
        const int t = s;
        const int n0 = blk * 16;
        // phase 1: x[b,t,:] . W_ih_0[c,:]   (K = 256)
        const _Float16* arow = ws16 + X16_OFF + (size_t)(m0 + r) * (kT * kI) + (size_t)t * kI;
        const _Float16* brow = ws16 + WIH0_OFF + (size_t)(n0 + r) * kI;
        acc = mfma_rows<kI>(arow, brow, acc, q);
        // phase 2: h_prev[b,:] . W_hh_0[c,:] (K = 512); h_prev = out0[t-1] slab
        const _Float16* hbase = (t == 0) ? (ws16 + HINIT0_OFF)
                                         : (ws16 + OUT0_OFF + (size_t)(t - 1) * (kB * kH));
        arow = hbase + (size_t)(m0 + r) * kH;
        brow = ws16 + WHH0_OFF + (size_t)(n0 + r) * kH;
        acc = mfma_rows<kH>(arow, brow, acc, q);

        const int c = n0 + r;
        const float bias = bih0[c] + bhh0[c];
        _Float16* outslab = ws16 + OUT0_OFF + (size_t)t * (kB * kH);
#pragma unroll
        for (int i = 0; i < 4; ++i) {
            const int b_ = m0 + q * 4 + i;
            const float v = tanhf(acc[i] + bias);
            outslab[(size_t)b_ * kH + c] = (_Float16)v;
        }
    } else {
        // ---- layer 1, t = s - 1 ----
        if (s < 1) return;
        const int t = s - 1;
        const int n0 = (blk - 32) * 16;
        // phase 1: out0[t][b,:] . W_ih_1[c,:]  (K = 512)
        const _Float16* arow = ws16 + OUT0_OFF + (size_t)t * (kB * kH) + (size_t)(m0 + r) * kH;
        const _Float16* brow = ws16 + WIH1_OFF + (size_t)(n0 + r) * kH;
        acc = mfma_rows<kH>(arow, brow, acc, q);
        // phase 2: h1_prev[b,:] . W_hh_1[c,:]  (K = 512)
        const _Float16* hbase = (t == 0) ? (ws16 + HINIT1_OFF)
                                         : (ws16 + H1BUF_OFF + (size_t)((t - 1) & 1) * (kB * kH));
        arow = hbase + (size_t)(m0 + r) * kH;
        brow = ws16 + WHH1_OFF + (size_t)(n0 + r) * kH;
        acc = mfma_rows<kH>(arow, brow, acc, q);

        const int c = n0 + r;
        const float bias = bih1[c] + bhh1[c];
        _Float16* hout = ws16 + H1BUF_OFF + (size_t)(t & 1) * (kB * kH);
#pragma unroll
        for (int i = 0; i < 4; ++i) {
            const int b_ = m0 + q * 4 + i;
            const float v = tanhf(acc[i] + bias);
            out1[((size_t)b_ * kT + t) * kH + c] = v;            // fp32 output
            hout[(size_t)b_ * kH + c] = (_Float16)v;             // fp16 state
        }
    }
}

// write h_n = [h0_final; h1_final] as fp32 after out1
__global__ void finalize_kernel(const _Float16* __restrict__ ws16,
                                float* __restrict__ out) {
    const int idx = blockIdx.x * blockDim.x + threadIdx.x;  // 0 .. 2*B*H-1
    float* hn = out + (size_t)kB * kT * kH;
    const int n = kB * kH;
    if (idx < n) {
        // layer0 final state = out0[T-1] slab
        hn[idx] = (float)ws16[OUT0_OFF + (size_t)(kT - 1) * (kB * kH) + idx];
    } else if (idx < 2 * n) {
        // layer1 final state: written at t=T-1 into h1buf[(T-1)&1] = h1buf[1]
        hn[idx] = (float)ws16[H1BUF_OFF + (size_t)((kT - 1) & 1) * (kB * kH) + (idx - n)];
    }
}

extern "C" void kernel_launch(void* const* d_in, const int* in_sizes, int n_in,
                              void* d_out, int out_size, void* d_ws, size_t ws_size,
                              hipStream_t stream) {
    const float* x    = (const float*)d_in[0];
    const float* h0in = (const float*)d_in[1];
    const float* wih0 = (const float*)d_in[2];
    const float* whh0 = (const float*)d_in[3];
    const float* bih0 = (const float*)d_in[4];
    const float* bhh0 = (const float*)d_in[5];
    const float* wih1 = (const float*)d_in[6];
    const float* whh1 = (const float*)d_in[7];
    const float* bih1 = (const float*)d_in[8];
    const float* bhh1 = (const float*)d_in[9];
    float* out = (float*)d_out;
    _Float16* ws16 = (_Float16*)d_ws;

    // fp32 -> fp16 conversions into ws
    f32_to_f16_kernel<<<1024, 256, 0, stream>>>(x, ws16 + X16_OFF, X16_N);
    f32_to_f16_kernel<<<128, 256, 0, stream>>>(wih0, ws16 + WIH0_OFF, WIH0_N);
    f32_to_f16_kernel<<<256, 256, 0, stream>>>(whh0, ws16 + WHH0_OFF, WHH0_N);
    f32_to_f16_kernel<<<256, 256, 0, stream>>>(wih1, ws16 + WIH1_OFF, WIH1_N);
    f32_to_f16_kernel<<<256, 256, 0, stream>>>(whh1, ws16 + WHH1_OFF, WHH1_N);
    f32_to_f16_kernel<<<32, 256, 0, stream>>>(h0in, ws16 + HINIT0_OFF, (size_t)kB * kH);
    f32_to_f16_kernel<<<32, 256, 0, stream>>>(h0in + (size_t)kB * kH, ws16 + HINIT1_OFF,
                                              (size_t)kB * kH);

    // pipelined scan: step s computes layer0@t=s and layer1@t=s-1
    for (int s = 0; s <= kT; ++s) {
        step_kernel<<<64, 256, 0, stream>>>(ws16, out, bih0, bhh0, bih1, bhh1, s);
    }

    finalize_kernel<<<(2 * kB * kH) / 256, 256, 0, stream>>>(ws16, out);
}